// Round 11
// baseline (1159.767 us; speedup 1.0000x reference)
//
#include <hip/hip_runtime.h>
#include <hip/hip_bf16.h>
#include <hip/hip_fp16.h>

// Bahdanau location-sensitive attention, fused f16-MFMA implementation.
// R11: Af f16 materialization (sequential-HBM k_cvt; loc appended -> uniform K)
//      + k_main 128x256 tile, 8 waves, both operands f16 gload_lds, 52 KB LDS
//      -> 3 blocks/CU. ctx reads Af (f16, L3-hot).
// B=32 T=1536 H=1024 CTX=1024 CONV_OUT=32

constexpr int kB = 32, kT = 1536, kH = 1024, kC = 1024, kCO = 32;
constexpr int kM = kB * kT;      // 49152
constexpr int kKp = 1088;        // padded K: 1024 enc | 32 loc | 32 zero

typedef _Float16 f16;
typedef _Float16 f16x8 __attribute__((ext_vector_type(8)));
typedef float f32x4 __attribute__((ext_vector_type(4)));

// ---- ws layout (bytes) ----
constexpr size_t W2_A     = 0;                                   // kM*kKp f16 = 106.95 MB
constexpr size_t W2_B     = W2_A + (size_t)kM * kKp * 2;         // kC*kKp f16 = 2.23 MB
constexpr size_t W2_ADD   = W2_B + (size_t)kC * kKp * 2;         // kB*kC f32
constexpr size_t W2_SCORE = W2_ADD + (size_t)kB * kC * 4;        // 4*kM f32
constexpr size_t W2_CTXP  = W2_SCORE + (size_t)4 * kM * 4;       // 8*kB*kH f32

__device__ __forceinline__ void gload16(const void* g, void* l) {
    __builtin_amdgcn_global_load_lds(
        (const __attribute__((address_space(1))) void*)g,
        (__attribute__((address_space(3))) void*)l, 16, 0, 0);
}

// ---------------------------------------------------------------- cvt enc -> Af cols 0..1023 (sequential HBM)
__global__ void k_cvt(const float* __restrict__ enc, f16* __restrict__ Af) {
    int gid = blockIdx.x * 256 + threadIdx.x;       // < kM*kH/8
    int row = gid >> 7, c8 = gid & 127;
    const float* src = enc + (size_t)row * kH + c8 * 8;
    float4 e0 = *(const float4*)src;
    float4 e1 = *(const float4*)(src + 4);
    union { f16 h[8]; int4 q; } u;
    u.h[0] = (f16)e0.x; u.h[1] = (f16)e0.y; u.h[2] = (f16)e0.z; u.h[3] = (f16)e0.w;
    u.h[4] = (f16)e1.x; u.h[5] = (f16)e1.y; u.h[6] = (f16)e1.z; u.h[7] = (f16)e1.w;
    *(int4*)(Af + (size_t)row * kKp + c8 * 8) = u.q;
}

// ---------------------------------------------------------------- conv1d -> Af cols 1024..1087
__global__ void k_loc(const float* __restrict__ la, const float* __restrict__ cw,
                      const float* __restrict__ cb, f16* __restrict__ Af) {
    int m = blockIdx.x * 256 + threadIdx.x;          // < kM
    int b = m / kT, t = m - b * kT;
    float x0 = (t > 0)      ? la[(size_t)b * kT + t - 1] : 0.f;
    float x1 = la[(size_t)b * kT + t];
    float x2 = (t < kT - 1) ? la[(size_t)b * kT + t + 1] : 0.f;
    union { f16 h[32]; int4 q[4]; } u;
#pragma unroll
    for (int k = 0; k < 32; ++k)
        u.h[k] = (f16)(cw[k * 3] * x0 + cw[k * 3 + 1] * x1 + cw[k * 3 + 2] * x2 + cb[k]);
    int4* dst = (int4*)(Af + (size_t)m * kKp + kH);
    dst[0] = u.q[0]; dst[1] = u.q[1]; dst[2] = u.q[2]; dst[3] = u.q[3];
    int4 z = {0, 0, 0, 0};
    dst[4] = z; dst[5] = z; dst[6] = z; dst[7] = z;   // zero pad 1056..1087
}

// ---------------------------------------------------------------- B pack [kC][1088] f16
__global__ void k_prep_b2(const float* __restrict__ V, const float* __restrict__ U,
                          f16* __restrict__ Bf) {
    int c = blockIdx.x;
    for (int k = threadIdx.x; k < kKp; k += 256) {
        float v = (k < kH) ? V[(size_t)c * kH + k]
                : (k < kH + kCO) ? U[(size_t)c * kCO + (k - kH)] : 0.f;
        Bf[(size_t)c * kKp + k] = (f16)v;
    }
}

// ---------------------------------------------------------------- prep add = dec@W^T + bias
__global__ void k_prep_add(const float* __restrict__ dec, const float* __restrict__ W,
                           const float* __restrict__ bias, float* __restrict__ add) {
    __shared__ float dl[kH];
    int bb = blockIdx.x >> 2;
    int cc = (blockIdx.x & 3) * 256 + threadIdx.x;
    *(float4*)&dl[threadIdx.x * 4] = *(const float4*)&dec[(size_t)bb * kH + threadIdx.x * 4];
    __syncthreads();
    float acc = bias[cc];
    const float* wr = W + (size_t)cc * kH;
    for (int h = 0; h < kH; h += 4) {
        float4 wv = *(const float4*)&wr[h];
        acc += wv.x * dl[h] + wv.y * dl[h + 1] + wv.z * dl[h + 2] + wv.w * dl[h + 3];
    }
    add[(size_t)bb * kC + cc] = acc;
}

// ---------------------------------------------------------------- fused main GEMM
// Tile 128(M) x 256(N), BK=64, 512 thr = 8 waves (2M x 4N), per-wave 64x64.
// LDS (53248 B): As f16 [128 rows][8 chunks 16B, phys c ^ (row&7)] @0 (16 KB);
//   Bs f16 [256 rows][8 chunks] @16384 (32 KB); add_l @49152; w_l @50176;
//   sred @51200. Simple 2-barrier loop; 3 blocks/CU (24 waves) — three
//   independent barrier groups hide each other's stage drains; Af is L3-hot.
__launch_bounds__(512, 6)
__global__ void k_main(const f16* __restrict__ Ag, const f16* __restrict__ Bg,
                       const float* __restrict__ add, const float* __restrict__ wvec,
                       float* __restrict__ spart) {
    __shared__ __align__(16) char smem[53248];
    float* add_l = (float*)(smem + 49152);
    float* w_l   = (float*)(smem + 50176);
    float (*sred)[64][4] = (float (*)[64][4])(smem + 51200);

    const int tid = threadIdx.x, lane = tid & 63, wave = tid >> 6;
    const int wm = wave >> 2, wn = wave & 3;
    // bijective XCD swizzle: 1536 blocks = 8 XCDs x 192; nt fastest (4 per A strip)
    const int raw = blockIdx.x;
    const int lin = (raw & 7) * 192 + (raw >> 3);
    const int mt = lin >> 2, nt = lin & 3;
    const int m0 = mt * 128, n0 = nt * 256;
    const int bb = m0 / kT;                          // 128 | 1536

    if (tid < 256) {
        add_l[tid] = add[(size_t)bb * kC + n0 + tid];
        w_l[tid]   = wvec[n0 + tid];
    }

    f32x4 acc[4][4];
#pragma unroll
    for (int i = 0; i < 4; ++i)
#pragma unroll
        for (int j = 0; j < 4; ++j) acc[i][j] = (f32x4){0.f, 0.f, 0.f, 0.f};

    // A gload (f16): 2 instr/thread-group, each covers 8 rows x 128B.
    // lane l -> row l>>3, LDS chunk l&7; src chunk = (l&7) ^ (row&7).
    const int rG = lane >> 3;
    const int gc = (lane & 7) ^ (rG & 7);
    const f16* aS[2];
#pragma unroll
    for (int j = 0; j < 2; ++j)
        aS[j] = Ag + (size_t)(m0 + wave * 16 + j * 8 + rG) * kKp + gc * 8;
    // B gload (f16): 4 instr, rows wave*32 + j*8 + rG
    const f16* bS[4];
#pragma unroll
    for (int j = 0; j < 4; ++j)
        bS[j] = Bg + (size_t)(n0 + wave * 32 + j * 8 + rG) * kKp + gc * 8;

    const unsigned aDst = wave * 2048u;
    const unsigned bDst = 16384u + wave * 4096u;
    const int g = lane >> 4, rl = lane & 15;

    for (int t = 0; t < 17; ++t) {     // 17 uniform K-steps (16 enc + 1 loc|U|pad)
        // ---- stage K-step t
#pragma unroll
        for (int j = 0; j < 2; ++j) gload16(aS[j] + t * 64, smem + aDst + j * 1024);
#pragma unroll
        for (int j = 0; j < 4; ++j) gload16(bS[j] + t * 64, smem + bDst + j * 1024);
        __syncthreads();
        // ---- compute: 2 kk x 16 MFMA
#pragma unroll
        for (int kk = 0; kk < 2; ++kk) {
            f16x8 bfv[4], af[4];
#pragma unroll
            for (int ni = 0; ni < 4; ++ni)
                bfv[ni] = *(const f16x8*)(smem + 16384 + (wn * 64 + ni * 16 + rl) * 128
                                          + (((kk * 4 + g) ^ (rl & 7)) << 4));
#pragma unroll
            for (int mi = 0; mi < 4; ++mi)
                af[mi] = *(const f16x8*)(smem + (wm * 64 + mi * 16 + rl) * 128
                                         + (((kk * 4 + g) ^ (rl & 7)) << 4));
            __builtin_amdgcn_s_setprio(1);
#pragma unroll
            for (int mi = 0; mi < 4; ++mi)
#pragma unroll
                for (int ni = 0; ni < 4; ++ni)
                    acc[mi][ni] = __builtin_amdgcn_mfma_f32_16x16x32_f16(af[mi], bfv[ni], acc[mi][ni], 0, 0, 0);
            __builtin_amdgcn_s_setprio(0);
        }
        __syncthreads();
    }

    // ---- epilogue: e = tanh(acc + add[c]); partial score = sum_c e*w[c]
#pragma unroll
    for (int mi = 0; mi < 4; ++mi) {
#pragma unroll
        for (int i = 0; i < 4; ++i) {
            float p = 0.f;
#pragma unroll
            for (int ni = 0; ni < 4; ++ni) {
                int cl = wn * 64 + ni * 16 + rl;
                float e = tanhf(acc[mi][ni][i] + add_l[cl]);
                p += e * w_l[cl];
            }
            p += __shfl_xor(p, 1);
            p += __shfl_xor(p, 2);
            p += __shfl_xor(p, 4);
            p += __shfl_xor(p, 8);
            if (rl == 0) sred[wm][mi * 16 + g * 4 + i][wn] = p;
        }
    }
    __syncthreads();
    if (tid < 128) {
        int r = tid & 63, w2 = tid >> 6;
        float s = sred[w2][r][0] + sred[w2][r][1] + sred[w2][r][2] + sred[w2][r][3];
        spart[(size_t)nt * kM + m0 + tid] = s;
    }
}

// ---------------------------------------------------------------- softmax over T (4 partials)
__global__ void k_softmax(const float* __restrict__ spart, float* __restrict__ out_align) {
    __shared__ float red[256];
    int b = blockIdx.x, tid = threadIdx.x;
    float v[6];
    float mx = -1e30f;
#pragma unroll
    for (int i = 0; i < 6; ++i) {
        size_t idx = (size_t)b * kT + tid + i * 256;
        float s = spart[idx] + spart[kM + idx] + spart[2 * (size_t)kM + idx] + spart[3 * (size_t)kM + idx];
        v[i] = s; mx = fmaxf(mx, s);
    }
    red[tid] = mx; __syncthreads();
    for (int o = 128; o > 0; o >>= 1) { if (tid < o) red[tid] = fmaxf(red[tid], red[tid + o]); __syncthreads(); }
    mx = red[0]; __syncthreads();
    float sum = 0.f;
#pragma unroll
    for (int i = 0; i < 6; ++i) { v[i] = expf(v[i] - mx); sum += v[i]; }
    red[tid] = sum; __syncthreads();
    for (int o = 128; o > 0; o >>= 1) { if (tid < o) red[tid] += red[tid + o]; __syncthreads(); }
    float inv = 1.f / red[0];
#pragma unroll
    for (int i = 0; i < 6; ++i)
        out_align[(size_t)b * kT + tid + i * 256] = v[i] * inv;
}

// ---------------------------------------------------------------- context (reads Af f16, L3-hot)
__global__ void k_ctx_part(const f16* __restrict__ Af, const float* __restrict__ align,
                           float* __restrict__ cpart) {
    __shared__ float al[192];
    int ci = blockIdx.x, b = blockIdx.y, tid = threadIdx.x;
    if (tid < 192) al[tid] = align[(size_t)b * kT + ci * 192 + tid];
    __syncthreads();
    float4 acc = {0.f, 0.f, 0.f, 0.f};
    const f16* ep = Af + ((size_t)b * kT + (size_t)ci * 192) * kKp + tid * 4;
    for (int t = 0; t < 192; ++t) {
        float a = al[t];
        f16 e0 = ep[(size_t)t * kKp + 0], e1 = ep[(size_t)t * kKp + 1];
        f16 e2 = ep[(size_t)t * kKp + 2], e3 = ep[(size_t)t * kKp + 3];
        acc.x += a * (float)e0; acc.y += a * (float)e1;
        acc.z += a * (float)e2; acc.w += a * (float)e3;
    }
    *(float4*)&cpart[((size_t)ci * kB + b) * kH + tid * 4] = acc;
}

__global__ void k_ctx_red(const float* __restrict__ cpart, float* __restrict__ out_ctx) {
    int idx = blockIdx.x * 256 + threadIdx.x;
    float s = 0.f;
#pragma unroll
    for (int ci = 0; ci < 8; ++ci) s += cpart[(size_t)ci * kB * kH + idx];
    out_ctx[idx] = s;
}

// ---------------------------------------------------------------- launch
extern "C" void kernel_launch(void* const* d_in, const int* in_sizes, int n_in,
                              void* d_out, int out_size, void* d_ws, size_t ws_size,
                              hipStream_t stream) {
    const float* dec  = (const float*)d_in[0];
    const float* enc  = (const float*)d_in[1];
    const float* la   = (const float*)d_in[2];
    const float* W    = (const float*)d_in[3];
    const float* V    = (const float*)d_in[4];
    const float* U    = (const float*)d_in[5];
    const float* bias = (const float*)d_in[6];
    const float* wv   = (const float*)d_in[7];
    const float* cw   = (const float*)d_in[8];
    const float* cb   = (const float*)d_in[9];

    char* ws = (char*)d_ws;
    f16* Af      = (f16*)(ws + W2_A);
    f16* Bf      = (f16*)(ws + W2_B);
    float* add   = (float*)(ws + W2_ADD);
    float* spart = (float*)(ws + W2_SCORE);
    float* cpart = (float*)(ws + W2_CTXP);

    float* out_ctx   = (float*)d_out;            // (B,H)
    float* out_align = (float*)d_out + kB * kH;  // (B,T)

    hipLaunchKernelGGL(k_prep_b2,  dim3(kC),             dim3(256), 0, stream, V, U, Bf);
    hipLaunchKernelGGL(k_loc,      dim3(kM / 256),       dim3(256), 0, stream, la, cw, cb, Af);
    hipLaunchKernelGGL(k_cvt,      dim3(kM * kH / 8 / 256), dim3(256), 0, stream, enc, Af);
    hipLaunchKernelGGL(k_prep_add, dim3(kB * 4),         dim3(256), 0, stream, dec, W, bias, add);
    hipLaunchKernelGGL(k_main,     dim3((kM / 128) * 4), dim3(512), 0, stream, Af, Bf, add, wv, spart);
    hipLaunchKernelGGL(k_softmax,  dim3(kB),             dim3(256), 0, stream, spart, out_align);
    hipLaunchKernelGGL(k_ctx_part, dim3(8, kB),          dim3(256), 0, stream, Af, out_align, cpart);
    hipLaunchKernelGGL(k_ctx_red,  dim3(kB * kH / 256),  dim3(256), 0, stream, cpart, out_ctx);
}

// Round 12
// 239.649 us; speedup vs baseline: 4.8394x; 4.8394x over previous
//
#include <hip/hip_runtime.h>
#include <hip/hip_bf16.h>
#include <hip/hip_fp16.h>

// Bahdanau location-sensitive attention, fused f16-MFMA implementation.
// R12: R11's Af-f16 + gload_lds design at FEASIBLE occupancy: 128x128 tile,
//      256 thr / 4 waves, __launch_bounds__(256,4) -> 128 regs/wave (no spill),
//      ~34 KB LDS -> 4 blocks/CU = 4 independent barrier groups.
//      (R11's (512,6) capped regs at 85 and spilled the 64-AGPR accumulator:
//       VGPR 40, 4.7 GB scratch traffic, 1070 us. Structural lesson recorded.)
// B=32 T=1536 H=1024 CTX=1024 CONV_OUT=32

constexpr int kB = 32, kT = 1536, kH = 1024, kC = 1024, kCO = 32;
constexpr int kM = kB * kT;      // 49152
constexpr int kKp = 1088;        // padded K: 1024 enc | 32 loc | 32 zero

typedef _Float16 f16;
typedef _Float16 f16x8 __attribute__((ext_vector_type(8)));
typedef float f32x4 __attribute__((ext_vector_type(4)));

// ---- ws layout (bytes) ----
constexpr size_t W2_A     = 0;                                   // kM*kKp f16 = 106.95 MB
constexpr size_t W2_B     = W2_A + (size_t)kM * kKp * 2;         // kC*kKp f16 = 2.23 MB
constexpr size_t W2_ADD   = W2_B + (size_t)kC * kKp * 2;         // kB*kC f32
constexpr size_t W2_SCORE = W2_ADD + (size_t)kB * kC * 4;        // 8*kM f32 partials
constexpr size_t W2_CTXP  = W2_SCORE + (size_t)8 * kM * 4;       // 8*kB*kH f32

__device__ __forceinline__ void gload16(const void* g, void* l) {
    __builtin_amdgcn_global_load_lds(
        (const __attribute__((address_space(1))) void*)g,
        (__attribute__((address_space(3))) void*)l, 16, 0, 0);
}

// ---------------------------------------------------------------- cvt enc -> Af cols 0..1023 (sequential HBM)
__global__ void k_cvt(const float* __restrict__ enc, f16* __restrict__ Af) {
    int gid = blockIdx.x * 256 + threadIdx.x;       // < kM*kH/8
    int row = gid >> 7, c8 = gid & 127;
    const float* src = enc + (size_t)row * kH + c8 * 8;
    float4 e0 = *(const float4*)src;
    float4 e1 = *(const float4*)(src + 4);
    union { f16 h[8]; int4 q; } u;
    u.h[0] = (f16)e0.x; u.h[1] = (f16)e0.y; u.h[2] = (f16)e0.z; u.h[3] = (f16)e0.w;
    u.h[4] = (f16)e1.x; u.h[5] = (f16)e1.y; u.h[6] = (f16)e1.z; u.h[7] = (f16)e1.w;
    *(int4*)(Af + (size_t)row * kKp + c8 * 8) = u.q;
}

// ---------------------------------------------------------------- conv1d -> Af cols 1024..1087
__global__ void k_loc(const float* __restrict__ la, const float* __restrict__ cw,
                      const float* __restrict__ cb, f16* __restrict__ Af) {
    int m = blockIdx.x * 256 + threadIdx.x;          // < kM
    int b = m / kT, t = m - b * kT;
    float x0 = (t > 0)      ? la[(size_t)b * kT + t - 1] : 0.f;
    float x1 = la[(size_t)b * kT + t];
    float x2 = (t < kT - 1) ? la[(size_t)b * kT + t + 1] : 0.f;
    union { f16 h[32]; int4 q[4]; } u;
#pragma unroll
    for (int k = 0; k < 32; ++k)
        u.h[k] = (f16)(cw[k * 3] * x0 + cw[k * 3 + 1] * x1 + cw[k * 3 + 2] * x2 + cb[k]);
    int4* dst = (int4*)(Af + (size_t)m * kKp + kH);
    dst[0] = u.q[0]; dst[1] = u.q[1]; dst[2] = u.q[2]; dst[3] = u.q[3];
    int4 z = {0, 0, 0, 0};
    dst[4] = z; dst[5] = z; dst[6] = z; dst[7] = z;   // zero pad 1056..1087
}

// ---------------------------------------------------------------- B pack [kC][1088] f16
__global__ void k_prep_b2(const float* __restrict__ V, const float* __restrict__ U,
                          f16* __restrict__ Bf) {
    int c = blockIdx.x;
    for (int k = threadIdx.x; k < kKp; k += 256) {
        float v = (k < kH) ? V[(size_t)c * kH + k]
                : (k < kH + kCO) ? U[(size_t)c * kCO + (k - kH)] : 0.f;
        Bf[(size_t)c * kKp + k] = (f16)v;
    }
}

// ---------------------------------------------------------------- prep add = dec@W^T + bias
__global__ void k_prep_add(const float* __restrict__ dec, const float* __restrict__ W,
                           const float* __restrict__ bias, float* __restrict__ add) {
    __shared__ float dl[kH];
    int bb = blockIdx.x >> 2;
    int cc = (blockIdx.x & 3) * 256 + threadIdx.x;
    *(float4*)&dl[threadIdx.x * 4] = *(const float4*)&dec[(size_t)bb * kH + threadIdx.x * 4];
    __syncthreads();
    float acc = bias[cc];
    const float* wr = W + (size_t)cc * kH;
    for (int h = 0; h < kH; h += 4) {
        float4 wv = *(const float4*)&wr[h];
        acc += wv.x * dl[h] + wv.y * dl[h + 1] + wv.z * dl[h + 2] + wv.w * dl[h + 3];
    }
    add[(size_t)bb * kC + cc] = acc;
}

// ---------------------------------------------------------------- fused main GEMM
// Tile 128(M) x 128(N), BK=64, 256 thr = 4 waves (2M x 2N), per-wave 64x64.
// LDS (34816 B): As f16 [128 rows][8 chunks 16B, phys c ^ (row&7)] @0 (16 KB);
//   Bs f16 @16384 (16 KB); add_l @32768 (128 f32); w_l @33280; sred @33792.
// __launch_bounds__(256,4): 128 regs/wave (acc 64 AGPR + ~50 VGPR fits),
// 4 blocks/CU = 4 independent barrier groups hiding each other's drains.
__launch_bounds__(256, 4)
__global__ void k_main(const f16* __restrict__ Ag, const f16* __restrict__ Bg,
                       const float* __restrict__ add, const float* __restrict__ wvec,
                       float* __restrict__ spart) {
    __shared__ __align__(16) char smem[34816];
    float* add_l = (float*)(smem + 32768);
    float* w_l   = (float*)(smem + 33280);
    float (*sred)[64][2] = (float (*)[64][2])(smem + 33792);

    const int tid = threadIdx.x, lane = tid & 63, wave = tid >> 6;
    const int wm = wave >> 1, wn = wave & 1;
    // bijective XCD swizzle: 3072 blocks = 8 XCDs x 384; nt fastest (8 per A strip)
    const int raw = blockIdx.x;
    const int lin = (raw & 7) * 384 + (raw >> 3);
    const int mt = lin >> 3, nt = lin & 7;
    const int m0 = mt * 128, n0 = nt * 128;
    const int bb = m0 / kT;                          // 128 | 1536

    if (tid < 128) {
        add_l[tid] = add[(size_t)bb * kC + n0 + tid];
        w_l[tid]   = wvec[n0 + tid];
    }

    f32x4 acc[4][4];
#pragma unroll
    for (int i = 0; i < 4; ++i)
#pragma unroll
        for (int j = 0; j < 4; ++j) acc[i][j] = (f32x4){0.f, 0.f, 0.f, 0.f};

    // gload mapping: each instr covers 8 rows x 128B; lane l -> row l>>3,
    // LDS chunk l&7; global src chunk = (l&7) ^ (row&7).
    const int rG = lane >> 3;
    const int gc = (lane & 7) ^ (rG & 7);
    const f16* aS[4]; const f16* bS[4];
#pragma unroll
    for (int j = 0; j < 4; ++j) {
        aS[j] = Ag + (size_t)(m0 + wave * 32 + j * 8 + rG) * kKp + gc * 8;
        bS[j] = Bg + (size_t)(n0 + wave * 32 + j * 8 + rG) * kKp + gc * 8;
    }
    const unsigned aDst = wave * 4096u;
    const unsigned bDst = 16384u + wave * 4096u;
    const int g = lane >> 4, rl = lane & 15;

    for (int t = 0; t < 17; ++t) {     // 17 uniform K-steps (16 enc + 1 loc|U|pad)
        // ---- stage K-step t: As 16 KB + Bs 16 KB
#pragma unroll
        for (int j = 0; j < 4; ++j) gload16(aS[j] + t * 64, smem + aDst + j * 1024);
#pragma unroll
        for (int j = 0; j < 4; ++j) gload16(bS[j] + t * 64, smem + bDst + j * 1024);
        __syncthreads();
        // ---- compute: 2 kk x 16 MFMA
#pragma unroll
        for (int kk = 0; kk < 2; ++kk) {
            f16x8 bfv[4], af[4];
#pragma unroll
            for (int ni = 0; ni < 4; ++ni)
                bfv[ni] = *(const f16x8*)(smem + 16384 + (wn * 64 + ni * 16 + rl) * 128
                                          + (((kk * 4 + g) ^ (rl & 7)) << 4));
#pragma unroll
            for (int mi = 0; mi < 4; ++mi)
                af[mi] = *(const f16x8*)(smem + (wm * 64 + mi * 16 + rl) * 128
                                         + (((kk * 4 + g) ^ (rl & 7)) << 4));
            __builtin_amdgcn_s_setprio(1);
#pragma unroll
            for (int mi = 0; mi < 4; ++mi)
#pragma unroll
                for (int ni = 0; ni < 4; ++ni)
                    acc[mi][ni] = __builtin_amdgcn_mfma_f32_16x16x32_f16(af[mi], bfv[ni], acc[mi][ni], 0, 0, 0);
            __builtin_amdgcn_s_setprio(0);
        }
        __syncthreads();
    }

    // ---- epilogue: e = tanh(acc + add[c]); partial score = sum_c e*w[c]
#pragma unroll
    for (int mi = 0; mi < 4; ++mi) {
#pragma unroll
        for (int i = 0; i < 4; ++i) {
            float p = 0.f;
#pragma unroll
            for (int ni = 0; ni < 4; ++ni) {
                int cl = wn * 64 + ni * 16 + rl;
                float e = tanhf(acc[mi][ni][i] + add_l[cl]);
                p += e * w_l[cl];
            }
            p += __shfl_xor(p, 1);
            p += __shfl_xor(p, 2);
            p += __shfl_xor(p, 4);
            p += __shfl_xor(p, 8);
            if (rl == 0) sred[wm][mi * 16 + g * 4 + i][wn] = p;
        }
    }
    __syncthreads();
    if (tid < 128) {
        int r = tid & 63, w2 = tid >> 6;
        float s = sred[w2][r][0] + sred[w2][r][1];
        spart[(size_t)nt * kM + m0 + tid] = s;
    }
}

// ---------------------------------------------------------------- softmax over T (8 partials)
__global__ void k_softmax(const float* __restrict__ spart, float* __restrict__ out_align) {
    __shared__ float red[256];
    int b = blockIdx.x, tid = threadIdx.x;
    float v[6];
    float mx = -1e30f;
#pragma unroll
    for (int i = 0; i < 6; ++i) {
        size_t idx = (size_t)b * kT + tid + i * 256;
        float s = 0.f;
#pragma unroll
        for (int p = 0; p < 8; ++p) s += spart[(size_t)p * kM + idx];
        v[i] = s; mx = fmaxf(mx, s);
    }
    red[tid] = mx; __syncthreads();
    for (int o = 128; o > 0; o >>= 1) { if (tid < o) red[tid] = fmaxf(red[tid], red[tid + o]); __syncthreads(); }
    mx = red[0]; __syncthreads();
    float sum = 0.f;
#pragma unroll
    for (int i = 0; i < 6; ++i) { v[i] = expf(v[i] - mx); sum += v[i]; }
    red[tid] = sum; __syncthreads();
    for (int o = 128; o > 0; o >>= 1) { if (tid < o) red[tid] += red[tid + o]; __syncthreads(); }
    float inv = 1.f / red[0];
#pragma unroll
    for (int i = 0; i < 6; ++i)
        out_align[(size_t)b * kT + tid + i * 256] = v[i] * inv;
}

// ---------------------------------------------------------------- context (reads Af f16, L3-hot)
__global__ void k_ctx_part(const f16* __restrict__ Af, const float* __restrict__ align,
                           float* __restrict__ cpart) {
    __shared__ float al[192];
    int ci = blockIdx.x, b = blockIdx.y, tid = threadIdx.x;
    if (tid < 192) al[tid] = align[(size_t)b * kT + ci * 192 + tid];
    __syncthreads();
    float4 acc = {0.f, 0.f, 0.f, 0.f};
    const f16* ep = Af + ((size_t)b * kT + (size_t)ci * 192) * kKp + tid * 4;
    for (int t = 0; t < 192; ++t) {
        float a = al[t];
        f16 e0 = ep[(size_t)t * kKp + 0], e1 = ep[(size_t)t * kKp + 1];
        f16 e2 = ep[(size_t)t * kKp + 2], e3 = ep[(size_t)t * kKp + 3];
        acc.x += a * (float)e0; acc.y += a * (float)e1;
        acc.z += a * (float)e2; acc.w += a * (float)e3;
    }
    *(float4*)&cpart[((size_t)ci * kB + b) * kH + tid * 4] = acc;
}

__global__ void k_ctx_red(const float* __restrict__ cpart, float* __restrict__ out_ctx) {
    int idx = blockIdx.x * 256 + threadIdx.x;
    float s = 0.f;
#pragma unroll
    for (int ci = 0; ci < 8; ++ci) s += cpart[(size_t)ci * kB * kH + idx];
    out_ctx[idx] = s;
}

// ---------------------------------------------------------------- launch
extern "C" void kernel_launch(void* const* d_in, const int* in_sizes, int n_in,
                              void* d_out, int out_size, void* d_ws, size_t ws_size,
                              hipStream_t stream) {
    const float* dec  = (const float*)d_in[0];
    const float* enc  = (const float*)d_in[1];
    const float* la   = (const float*)d_in[2];
    const float* W    = (const float*)d_in[3];
    const float* V    = (const float*)d_in[4];
    const float* U    = (const float*)d_in[5];
    const float* bias = (const float*)d_in[6];
    const float* wv   = (const float*)d_in[7];
    const float* cw   = (const float*)d_in[8];
    const float* cb   = (const float*)d_in[9];

    char* ws = (char*)d_ws;
    f16* Af      = (f16*)(ws + W2_A);
    f16* Bf      = (f16*)(ws + W2_B);
    float* add   = (float*)(ws + W2_ADD);
    float* spart = (float*)(ws + W2_SCORE);
    float* cpart = (float*)(ws + W2_CTXP);

    float* out_ctx   = (float*)d_out;            // (B,H)
    float* out_align = (float*)d_out + kB * kH;  // (B,T)

    hipLaunchKernelGGL(k_prep_b2,  dim3(kC),             dim3(256), 0, stream, V, U, Bf);
    hipLaunchKernelGGL(k_loc,      dim3(kM / 256),       dim3(256), 0, stream, la, cw, cb, Af);
    hipLaunchKernelGGL(k_cvt,      dim3(kM * kH / 8 / 256), dim3(256), 0, stream, enc, Af);
    hipLaunchKernelGGL(k_prep_add, dim3(kB * 4),         dim3(256), 0, stream, dec, W, bias, add);
    hipLaunchKernelGGL(k_main,     dim3((kM / 128) * 8), dim3(256), 0, stream, Af, Bf, add, wv, spart);
    hipLaunchKernelGGL(k_softmax,  dim3(kB),             dim3(256), 0, stream, spart, out_align);
    hipLaunchKernelGGL(k_ctx_part, dim3(8, kB),          dim3(256), 0, stream, Af, out_align, cpart);
    hipLaunchKernelGGL(k_ctx_red,  dim3(kB * kH / 256),  dim3(256), 0, stream, cpart, out_ctx);
}